// Round 1
// baseline (355.653 us; speedup 1.0000x reference)
//
#include <hip/hip_runtime.h>
#include <math.h>

// Problem constants
#define B_   16
#define C_   512
#define HW_  4096
#define T_   768
#define NH   12
#define DH   64

// Workspace layout (floats). Total = 4,149,440 floats ~= 15.8 MB.
#define OFF_QKT  0                    // [B][C][NH]      98304
#define OFF_QB   98304                // [B*NH]          192
#define OFF_SP   98496                // [4][B][NH][HW]  3145728 (partial scores)
#define OFF_ATTN 3244224              // [B][NH][HW]     786432
#define OFF_Y    4030656              // [B][NH][C]      98304
#define OFF_OUTT 4128960              // [B][T]          12288
#define OFF_Z    4141248              // [B][C]          8192

// ---------------------------------------------------------------------------
// Kernel A: qkT[b][c][h] = (1/8) * sum_dd t[b, h*64+dd] * Wk[h*64+dd, c]
//           qb[b*12+h]   = (1/8) * sum_dd t[b, h*64+dd] * bk[h*64+dd]
// grid 192 (b*12+h), block 512 (one thread per c)
__global__ __launch_bounds__(512) void qk_kernel(
    const float* __restrict__ t, const float* __restrict__ Wk,
    const float* __restrict__ bk, float* __restrict__ qkT,
    float* __restrict__ qb) {
  int bh = blockIdx.x;
  int b = bh / NH, h = bh % NH;
  __shared__ float tl[DH];
  int tid = threadIdx.x;
  if (tid < DH) tl[tid] = t[b * T_ + h * DH + tid];
  __syncthreads();
  int c = tid;
  float acc = 0.f;
#pragma unroll
  for (int dd = 0; dd < DH; ++dd)
    acc += tl[dd] * Wk[(h * DH + dd) * C_ + c];
  qkT[((size_t)b * C_ + c) * NH + h] = acc * 0.125f;
  if (tid == 0) {
    float s = 0.f;
    for (int dd = 0; dd < DH; ++dd) s += tl[dd] * bk[h * DH + dd];
    qb[bh] = s * 0.125f;
  }
}

// ---------------------------------------------------------------------------
// Kernel B: partial scores. sp[cs][b][h][m] = sum_{c in cs-range} qk[b,h,c]*x[b,c,m]
// grid (mt=8, cs=4, b=16) = 512 blocks, block 128; each thread owns 4 m (float4)
__global__ __launch_bounds__(128) void s_kernel(
    const float* __restrict__ x, const float* __restrict__ qkT,
    float* __restrict__ sp) {
  int mt = blockIdx.x;   // 0..7
  int cs = blockIdx.y;   // 0..3
  int b  = blockIdx.z;   // 0..15
  int tid = threadIdx.x; // 0..127

  __shared__ float qc[128 * NH]; // qk for this c-range, [c][h]
  const float* src = qkT + ((size_t)b * C_ + cs * 128) * NH;
  for (int i = tid; i < 128 * NH; i += 128) qc[i] = src[i];
  __syncthreads();

  int m0 = mt * 512 + tid * 4;
  float4 acc[NH];
#pragma unroll
  for (int h = 0; h < NH; ++h) acc[h] = make_float4(0.f, 0.f, 0.f, 0.f);

  const float* xb = x + (size_t)b * C_ * HW_ + (size_t)(cs * 128) * HW_ + m0;
#pragma unroll 4
  for (int c = 0; c < 128; ++c) {
    float4 xv = *(const float4*)(xb + (size_t)c * HW_);
    const float* q = qc + c * NH;
#pragma unroll
    for (int h = 0; h < NH; ++h) {
      float qh = q[h];
      acc[h].x += qh * xv.x; acc[h].y += qh * xv.y;
      acc[h].z += qh * xv.z; acc[h].w += qh * xv.w;
    }
  }
  float* spp = sp + ((size_t)cs * B_ * NH + (size_t)b * NH) * HW_ + m0;
#pragma unroll
  for (int h = 0; h < NH; ++h)
    *(float4*)(spp + (size_t)h * HW_) = acc[h];
}

// ---------------------------------------------------------------------------
// Kernel C: combine partials + qb, softmax over m=4096. grid 192, block 256.
__global__ __launch_bounds__(256) void softmax_kernel(
    const float* __restrict__ sp, const float* __restrict__ qb,
    float* __restrict__ attn) {
  int bh = blockIdx.x;
  int tid = threadIdx.x;
  float qbv = qb[bh];
  const float* p0 = sp + (size_t)bh * HW_;
  const size_t S = (size_t)B_ * NH * HW_;

  float sv[16];
  float vmax = -1e30f;
#pragma unroll
  for (int k = 0; k < 16; ++k) {
    int m = k * 256 + tid;
    float v = p0[m] + p0[S + m] + p0[2 * S + m] + p0[3 * S + m] + qbv;
    sv[k] = v;
    vmax = fmaxf(vmax, v);
  }
  for (int off = 32; off; off >>= 1) vmax = fmaxf(vmax, __shfl_xor(vmax, off));
  __shared__ float red[8];
  int w = tid >> 6;
  if ((tid & 63) == 0) red[w] = vmax;
  __syncthreads();
  vmax = fmaxf(fmaxf(red[0], red[1]), fmaxf(red[2], red[3]));

  float sum = 0.f;
#pragma unroll
  for (int k = 0; k < 16; ++k) { sv[k] = __expf(sv[k] - vmax); sum += sv[k]; }
  for (int off = 32; off; off >>= 1) sum += __shfl_xor(sum, off);
  if ((tid & 63) == 0) red[4 + w] = sum;
  __syncthreads();
  float inv = 1.f / (red[4] + red[5] + red[6] + red[7]);
#pragma unroll
  for (int k = 0; k < 16; ++k)
    attn[(size_t)bh * HW_ + k * 256 + tid] = sv[k] * inv;
}

// ---------------------------------------------------------------------------
// Kernel D: y[b][h][c] = sum_m attn[b,h,m] * x[b,c,m]
// grid (cg=128, b=16), block 256; each block handles 4 consecutive c rows.
__global__ __launch_bounds__(256) void y_kernel(
    const float* __restrict__ x, const float* __restrict__ attn,
    float* __restrict__ y) {
  int cg = blockIdx.x;   // 0..127
  int b  = blockIdx.y;   // 0..15
  int tid = threadIdx.x;
  int c0 = cg * 4;

  float acc[4][NH];
#pragma unroll
  for (int g = 0; g < 4; ++g)
#pragma unroll
    for (int h = 0; h < NH; ++h) acc[g][h] = 0.f;

  const float* xb = x + (size_t)b * C_ * HW_ + (size_t)c0 * HW_;
  const float* ab = attn + (size_t)b * NH * HW_;
#pragma unroll 2
  for (int k = 0; k < 16; ++k) {
    int m = k * 256 + tid;
    float a[NH];
#pragma unroll
    for (int h = 0; h < NH; ++h) a[h] = ab[(size_t)h * HW_ + m];
#pragma unroll
    for (int g = 0; g < 4; ++g) {
      float xv = xb[(size_t)g * HW_ + m];
#pragma unroll
      for (int h = 0; h < NH; ++h) acc[g][h] += a[h] * xv;
    }
  }
  // reduce 48 values across the block
#pragma unroll
  for (int g = 0; g < 4; ++g)
#pragma unroll
    for (int h = 0; h < NH; ++h)
      for (int off = 32; off; off >>= 1)
        acc[g][h] += __shfl_xor(acc[g][h], off);

  __shared__ float red[4][48];
  int w = tid >> 6, lane = tid & 63;
  if (lane == 0) {
#pragma unroll
    for (int g = 0; g < 4; ++g)
#pragma unroll
      for (int h = 0; h < NH; ++h) red[w][g * NH + h] = acc[g][h];
  }
  __syncthreads();
  if (tid < 48) {
    float s = red[0][tid] + red[1][tid] + red[2][tid] + red[3][tid];
    int g = tid / NH, h = tid % NH;
    y[((size_t)b * NH + h) * C_ + c0 + g] = s;
  }
}

// ---------------------------------------------------------------------------
// Kernel E: outT[b][t] = bv[t] + sum_c Wv[t,c] * y[b][t/64][c]
// wave per output; grid 3072, block 256 (4 waves)
__global__ __launch_bounds__(256) void out_kernel(
    const float* __restrict__ Wv, const float* __restrict__ bv,
    const float* __restrict__ y, float* __restrict__ outT) {
  int o = blockIdx.x * 4 + (threadIdx.x >> 6); // 0..12287
  int lane = threadIdx.x & 63;
  int b = o / T_, t = o % T_;
  int h = t / DH;
  const float* wr = Wv + (size_t)t * C_;
  const float* yr = y + ((size_t)b * NH + h) * C_;
  float s = 0.f;
#pragma unroll
  for (int j = 0; j < 8; ++j) { int c = j * 64 + lane; s += wr[c] * yr[c]; }
  for (int off = 32; off; off >>= 1) s += __shfl_xor(s, off);
  if (lane == 0) outT[o] = s + bv[t];
}

// ---------------------------------------------------------------------------
// Kernel F: z[b][c] = bo[c] + sum_t Wo[c,t] * outT[b][t]
// wave per output; grid 2048, block 256
__global__ __launch_bounds__(256) void z_kernel(
    const float* __restrict__ Wo, const float* __restrict__ bo,
    const float* __restrict__ outT, float* __restrict__ z) {
  int o = blockIdx.x * 4 + (threadIdx.x >> 6); // 0..8191
  int lane = threadIdx.x & 63;
  int b = o / C_, c = o % C_;
  const float* wr = Wo + (size_t)c * T_;
  const float* orr = outT + (size_t)b * T_;
  float s = 0.f;
#pragma unroll
  for (int j = 0; j < 12; ++j) { int t = j * 64 + lane; s += wr[t] * orr[t]; }
  for (int off = 32; off; off >>= 1) s += __shfl_xor(s, off);
  if (lane == 0) z[o] = s + bo[c];
}

// ---------------------------------------------------------------------------
// Kernel G: out[b,c,i,j] = cond[b,c,i,j] + z[b,c]   (float4 streaming)
__global__ __launch_bounds__(256) void add_kernel(
    const float* __restrict__ cond, const float* __restrict__ z,
    float* __restrict__ out) {
  size_t i4 = (size_t)blockIdx.x * 256 + threadIdx.x;
  size_t e = i4 * 4;
  int bc = (int)(e >> 12); // /4096 -> b*512+c
  float zv = z[bc];
  float4 cv = ((const float4*)cond)[i4];
  float4 r = make_float4(cv.x + zv, cv.y + zv, cv.z + zv, cv.w + zv);
  ((float4*)out)[i4] = r;
}

// ---------------------------------------------------------------------------
extern "C" void kernel_launch(void* const* d_in, const int* in_sizes, int n_in,
                              void* d_out, int out_size, void* d_ws, size_t ws_size,
                              hipStream_t stream) {
  const float* cond = (const float*)d_in[0];
  const float* t    = (const float*)d_in[1];
  const float* Wk   = (const float*)d_in[2];
  const float* bk   = (const float*)d_in[3];
  const float* Wv   = (const float*)d_in[4];
  const float* bv   = (const float*)d_in[5];
  const float* Wo   = (const float*)d_in[6];
  const float* bo   = (const float*)d_in[7];
  float* out = (float*)d_out;

  float* ws   = (float*)d_ws;
  float* qkT  = ws + OFF_QKT;
  float* qb   = ws + OFF_QB;
  float* sp   = ws + OFF_SP;
  float* attn = ws + OFF_ATTN;
  float* y    = ws + OFF_Y;
  float* outT = ws + OFF_OUTT;
  float* z    = ws + OFF_Z;

  hipLaunchKernelGGL(qk_kernel, dim3(B_ * NH), dim3(512), 0, stream,
                     t, Wk, bk, qkT, qb);
  hipLaunchKernelGGL(s_kernel, dim3(8, 4, B_), dim3(128), 0, stream,
                     cond, qkT, sp);
  hipLaunchKernelGGL(softmax_kernel, dim3(B_ * NH), dim3(256), 0, stream,
                     sp, qb, attn);
  hipLaunchKernelGGL(y_kernel, dim3(128, B_), dim3(256), 0, stream,
                     cond, attn, y);
  hipLaunchKernelGGL(out_kernel, dim3((B_ * T_) / 4), dim3(256), 0, stream,
                     Wv, bv, y, outT);
  hipLaunchKernelGGL(z_kernel, dim3((B_ * C_) / 4), dim3(256), 0, stream,
                     Wo, bo, outT, z);
  hipLaunchKernelGGL(add_kernel, dim3((out_size / 4 + 255) / 256), dim3(256), 0,
                     stream, cond, z, out);
}

// Round 2
// 329.753 us; speedup vs baseline: 1.0785x; 1.0785x over previous
//
#include <hip/hip_runtime.h>
#include <math.h>

// Problem constants
#define B_   16
#define C_   512
#define HW_  4096
#define T_   768
#define NH   12
#define DH   64

// Workspace layout (floats), parametrized by CS (c-split count):
//   qkT  @ 0            [B][C][NH]        98304
//   qb   @ 98304        [B*NH]            192
//   sp   @ 98496        [CS][B][NH][HW]   CS*786432
//   attn @ 98496+CS*786432   [B][NH][HW]  786432
//   y    @ attn+786432  [B][NH][C]        98304
//   outT @ y+98304      [B][T]            12288
//   z    @ outT+12288   [B][C]            8192

// ---------------------------------------------------------------------------
// Kernel A: qkT[b][c][h] = (1/8) * sum_dd t[b, h*64+dd] * Wk[h*64+dd, c]
//           qb[b*12+h]   = (1/8) * sum_dd t[b, h*64+dd] * bk[h*64+dd]
__global__ __launch_bounds__(512) void qk_kernel(
    const float* __restrict__ t, const float* __restrict__ Wk,
    const float* __restrict__ bk, float* __restrict__ qkT,
    float* __restrict__ qb) {
  int bh = blockIdx.x;
  int b = bh / NH, h = bh % NH;
  __shared__ float tl[DH];
  int tid = threadIdx.x;
  if (tid < DH) tl[tid] = t[b * T_ + h * DH + tid];
  __syncthreads();
  int c = tid;
  float acc = 0.f;
#pragma unroll
  for (int dd = 0; dd < DH; ++dd)
    acc += tl[dd] * Wk[(h * DH + dd) * C_ + c];
  qkT[((size_t)b * C_ + c) * NH + h] = acc * 0.125f;
  if (tid == 0) {
    float s = 0.f;
    for (int dd = 0; dd < DH; ++dd) s += tl[dd] * bk[h * DH + dd];
    qb[bh] = s * 0.125f;
  }
}

// ---------------------------------------------------------------------------
// Kernel B: partial scores. sp[cs][b][h][m] = sum_{c in cs-range} qk[b,h,c]*x[b,c,m]
// grid (mt=8, cs=CS, b=16), block 128; each thread owns one float4 of m.
// c-loop unrolled by 8 with hoisted loads for memory-level parallelism.
template <int CS>
__global__ __launch_bounds__(128) void s_kernel(
    const float* __restrict__ x, const float* __restrict__ qkT,
    float* __restrict__ sp) {
  constexpr int CB = C_ / CS;  // c per block
  int mt = blockIdx.x;
  int cs = blockIdx.y;
  int b  = blockIdx.z;
  int tid = threadIdx.x;

  __shared__ float qc[CB * NH];
  const float* src = qkT + ((size_t)b * C_ + cs * CB) * NH;
  for (int i = tid; i < CB * NH; i += 128) qc[i] = src[i];
  __syncthreads();

  int m0 = mt * 512 + tid * 4;
  float4 acc[NH];
#pragma unroll
  for (int h = 0; h < NH; ++h) acc[h] = make_float4(0.f, 0.f, 0.f, 0.f);

  const float* xb = x + (size_t)b * C_ * HW_ + (size_t)(cs * CB) * HW_ + m0;
  for (int c0 = 0; c0 < CB; c0 += 8) {
    float4 xv[8];
#pragma unroll
    for (int j = 0; j < 8; ++j)
      xv[j] = *(const float4*)(xb + (size_t)(c0 + j) * HW_);
#pragma unroll
    for (int j = 0; j < 8; ++j) {
      const float* q = qc + (c0 + j) * NH;
#pragma unroll
      for (int h = 0; h < NH; ++h) {
        float qh = q[h];
        acc[h].x += qh * xv[j].x; acc[h].y += qh * xv[j].y;
        acc[h].z += qh * xv[j].z; acc[h].w += qh * xv[j].w;
      }
    }
  }
  float* spp = sp + ((size_t)cs * B_ * NH + (size_t)b * NH) * HW_ + m0;
#pragma unroll
  for (int h = 0; h < NH; ++h)
    *(float4*)(spp + (size_t)h * HW_) = acc[h];
}

// ---------------------------------------------------------------------------
// Kernel C: combine partials + qb, softmax over m=4096.
// grid 192, block 1024 (16 waves); each thread owns one float4 of the row.
template <int CS>
__global__ __launch_bounds__(1024) void softmax_kernel(
    const float* __restrict__ sp, const float* __restrict__ qb,
    float* __restrict__ attn) {
  int bh = blockIdx.x;
  int tid = threadIdx.x;  // float4 index within the row
  float qbv = qb[bh];
  const size_t S4 = (size_t)B_ * NH * (HW_ / 4);
  const float4* p = (const float4*)sp + (size_t)bh * (HW_ / 4) + tid;

  float4 v = make_float4(qbv, qbv, qbv, qbv);
#pragma unroll
  for (int s = 0; s < CS; ++s) {
    float4 pv = p[s * S4];
    v.x += pv.x; v.y += pv.y; v.z += pv.z; v.w += pv.w;
  }

  float vmax = fmaxf(fmaxf(v.x, v.y), fmaxf(v.z, v.w));
  for (int off = 32; off; off >>= 1) vmax = fmaxf(vmax, __shfl_xor(vmax, off));
  __shared__ float redm[16], reds[16];
  int w = tid >> 6;
  if ((tid & 63) == 0) redm[w] = vmax;
  __syncthreads();
  vmax = redm[0];
#pragma unroll
  for (int i = 1; i < 16; ++i) vmax = fmaxf(vmax, redm[i]);

  v.x = __expf(v.x - vmax); v.y = __expf(v.y - vmax);
  v.z = __expf(v.z - vmax); v.w = __expf(v.w - vmax);
  float sum = v.x + v.y + v.z + v.w;
  for (int off = 32; off; off >>= 1) sum += __shfl_xor(sum, off);
  if ((tid & 63) == 0) reds[w] = sum;
  __syncthreads();
  float tot = reds[0];
#pragma unroll
  for (int i = 1; i < 16; ++i) tot += reds[i];
  float inv = 1.f / tot;
  v.x *= inv; v.y *= inv; v.z *= inv; v.w *= inv;
  ((float4*)attn)[(size_t)bh * (HW_ / 4) + tid] = v;
}

// ---------------------------------------------------------------------------
// Kernel D: y[b][h][c] = sum_m attn[b,h,m] * x[b,c,m]
// grid (cg=128, b=16), block 256; each block handles 4 consecutive c rows.
// float4 loads for both attn and x.
__global__ __launch_bounds__(256) void y_kernel(
    const float* __restrict__ x, const float* __restrict__ attn,
    float* __restrict__ y) {
  int cg = blockIdx.x;   // 0..127
  int b  = blockIdx.y;   // 0..15
  int tid = threadIdx.x;
  int c0 = cg * 4;

  float acc[4][NH] = {};
  const float4* xb = (const float4*)(x + (size_t)b * C_ * HW_ + (size_t)c0 * HW_);
  const float4* ab = (const float4*)(attn + (size_t)b * NH * HW_);
#pragma unroll 1
  for (int k = 0; k < 4; ++k) {
    int m4 = k * 256 + tid;
    float4 a[NH];
#pragma unroll
    for (int h = 0; h < NH; ++h) a[h] = ab[(size_t)h * (HW_ / 4) + m4];
#pragma unroll
    for (int g = 0; g < 4; ++g) {
      float4 xv = xb[(size_t)g * (HW_ / 4) + m4];
#pragma unroll
      for (int h = 0; h < NH; ++h)
        acc[g][h] += a[h].x * xv.x + a[h].y * xv.y + a[h].z * xv.z + a[h].w * xv.w;
    }
  }
  // reduce 48 values across the block
#pragma unroll
  for (int g = 0; g < 4; ++g)
#pragma unroll
    for (int h = 0; h < NH; ++h)
      for (int off = 32; off; off >>= 1)
        acc[g][h] += __shfl_xor(acc[g][h], off);

  __shared__ float red[4][48];
  int w = tid >> 6, lane = tid & 63;
  if (lane == 0) {
#pragma unroll
    for (int g = 0; g < 4; ++g)
#pragma unroll
      for (int h = 0; h < NH; ++h) red[w][g * NH + h] = acc[g][h];
  }
  __syncthreads();
  if (tid < 48) {
    float s = red[0][tid] + red[1][tid] + red[2][tid] + red[3][tid];
    int g = tid / NH, h = tid % NH;
    y[((size_t)b * NH + h) * C_ + c0 + g] = s;
  }
}

// ---------------------------------------------------------------------------
// Kernel E: outT[b][t] = bv[t] + sum_c Wv[t,c] * y[b][t/64][c]
__global__ __launch_bounds__(256) void out_kernel(
    const float* __restrict__ Wv, const float* __restrict__ bv,
    const float* __restrict__ y, float* __restrict__ outT) {
  int o = blockIdx.x * 4 + (threadIdx.x >> 6);
  int lane = threadIdx.x & 63;
  int b = o / T_, t = o % T_;
  int h = t / DH;
  const float* wr = Wv + (size_t)t * C_;
  const float* yr = y + ((size_t)b * NH + h) * C_;
  float s = 0.f;
#pragma unroll
  for (int j = 0; j < 8; ++j) { int c = j * 64 + lane; s += wr[c] * yr[c]; }
  for (int off = 32; off; off >>= 1) s += __shfl_xor(s, off);
  if (lane == 0) outT[o] = s + bv[t];
}

// ---------------------------------------------------------------------------
// Kernel F: z[b][c] = bo[c] + sum_t Wo[c,t] * outT[b][t]
__global__ __launch_bounds__(256) void z_kernel(
    const float* __restrict__ Wo, const float* __restrict__ bo,
    const float* __restrict__ outT, float* __restrict__ z) {
  int o = blockIdx.x * 4 + (threadIdx.x >> 6);
  int lane = threadIdx.x & 63;
  int b = o / C_, c = o % C_;
  const float* wr = Wo + (size_t)c * T_;
  const float* orr = outT + (size_t)b * T_;
  float s = 0.f;
#pragma unroll
  for (int j = 0; j < 12; ++j) { int t = j * 64 + lane; s += wr[t] * orr[t]; }
  for (int off = 32; off; off >>= 1) s += __shfl_xor(s, off);
  if (lane == 0) z[o] = s + bo[c];
}

// ---------------------------------------------------------------------------
// Kernel G: out[b,c,i,j] = cond[b,c,i,j] + z[b,c]
__global__ __launch_bounds__(256) void add_kernel(
    const float* __restrict__ cond, const float* __restrict__ z,
    float* __restrict__ out) {
  size_t i4 = (size_t)blockIdx.x * 256 + threadIdx.x;
  size_t e = i4 * 4;
  int bc = (int)(e >> 12);
  float zv = z[bc];
  float4 cv = ((const float4*)cond)[i4];
  float4 r = make_float4(cv.x + zv, cv.y + zv, cv.z + zv, cv.w + zv);
  ((float4*)out)[i4] = r;
}

// ---------------------------------------------------------------------------
template <int CS>
static void run_pipeline(const float* cond, const float* t, const float* Wk,
                         const float* bk, const float* Wv, const float* bv,
                         const float* Wo, const float* bo, float* out,
                         float* ws, int out_size, hipStream_t stream) {
  float* qkT  = ws;
  float* qb   = ws + 98304;
  float* sp   = ws + 98496;
  float* attn = sp + (size_t)CS * 786432;
  float* y    = attn + 786432;
  float* outT = y + 98304;
  float* z    = outT + 12288;

  hipLaunchKernelGGL(qk_kernel, dim3(B_ * NH), dim3(512), 0, stream,
                     t, Wk, bk, qkT, qb);
  hipLaunchKernelGGL((s_kernel<CS>), dim3(8, CS, B_), dim3(128), 0, stream,
                     cond, qkT, sp);
  hipLaunchKernelGGL((softmax_kernel<CS>), dim3(B_ * NH), dim3(1024), 0, stream,
                     sp, qb, attn);
  hipLaunchKernelGGL(y_kernel, dim3(128, B_), dim3(256), 0, stream,
                     cond, attn, y);
  hipLaunchKernelGGL(out_kernel, dim3((B_ * T_) / 4), dim3(256), 0, stream,
                     Wv, bv, y, outT);
  hipLaunchKernelGGL(z_kernel, dim3((B_ * C_) / 4), dim3(256), 0, stream,
                     Wo, bo, outT, z);
  hipLaunchKernelGGL(add_kernel, dim3((out_size / 4 + 255) / 256), dim3(256), 0,
                     stream, cond, z, out);
}

extern "C" void kernel_launch(void* const* d_in, const int* in_sizes, int n_in,
                              void* d_out, int out_size, void* d_ws, size_t ws_size,
                              hipStream_t stream) {
  const float* cond = (const float*)d_in[0];
  const float* t    = (const float*)d_in[1];
  const float* Wk   = (const float*)d_in[2];
  const float* bk   = (const float*)d_in[3];
  const float* Wv   = (const float*)d_in[4];
  const float* bv   = (const float*)d_in[5];
  const float* Wo   = (const float*)d_in[6];
  const float* bo   = (const float*)d_in[7];
  float* out = (float*)d_out;
  float* ws  = (float*)d_ws;

  // floats needed for CS=8: 98496 + 8*786432 + 786432 + 98304 + 12288 + 8192
  const size_t need8 = (size_t)(98496 + 8 * 786432 + 786432 + 98304 + 12288 + 8192) * 4;
  if (ws_size >= need8) {
    run_pipeline<8>(cond, t, Wk, bk, Wv, bv, Wo, bo, out, ws, out_size, stream);
  } else {
    run_pipeline<4>(cond, t, Wk, bk, Wv, bv, Wo, bo, out, ws, out_size, stream);
  }
}

// Round 4
// 322.849 us; speedup vs baseline: 1.1016x; 1.0214x over previous
//
#include <hip/hip_runtime.h>
#include <math.h>

// Problem constants
#define B_   16
#define C_   512
#define HW_  4096
#define T_   768
#define NH   12
#define DH   64

typedef float nfloat4 __attribute__((ext_vector_type(4)));

// Workspace layout (floats), parametrized by CS (c-split count):
//   qkT  @ 0            [B][C][NH]        98304
//   qb   @ 98304        [B*NH]            192
//   sp   @ 98496        [CS][B][NH][HW]   CS*786432
//   attn @ 98496+CS*786432   [B][NH][HW]  786432
//   y    @ attn+786432  [B][NH][C]        98304
//   outT @ y+98304      [B][T]            12288
//   z    @ outT+12288   [B][C]            8192

// ---------------------------------------------------------------------------
// Kernel A: qkT[b][c][h] = (1/8) * sum_dd t[b, h*64+dd] * Wk[h*64+dd, c]
//           qb[b*12+h]   = (1/8) * sum_dd t[b, h*64+dd] * bk[h*64+dd]
__global__ __launch_bounds__(512) void qk_kernel(
    const float* __restrict__ t, const float* __restrict__ Wk,
    const float* __restrict__ bk, float* __restrict__ qkT,
    float* __restrict__ qb) {
  int bh = blockIdx.x;
  int b = bh / NH, h = bh % NH;
  __shared__ float tl[DH];
  int tid = threadIdx.x;
  if (tid < DH) tl[tid] = t[b * T_ + h * DH + tid];
  __syncthreads();
  int c = tid;
  float acc = 0.f;
#pragma unroll
  for (int dd = 0; dd < DH; ++dd)
    acc += tl[dd] * Wk[(h * DH + dd) * C_ + c];
  qkT[((size_t)b * C_ + c) * NH + h] = acc * 0.125f;
  if (tid == 0) {
    float s = 0.f;
    for (int dd = 0; dd < DH; ++dd) s += tl[dd] * bk[h * DH + dd];
    qb[bh] = s * 0.125f;
  }
}

// ---------------------------------------------------------------------------
// Kernel B: partial scores. sp[cs][b][h][m] = sum_{c in cs-range} qk[b,h,c]*x[b,c,m]
// grid (mt=8, cs=CS, b=16), block 128; each thread owns one float4 of m.
// 16 x-loads hoisted per group: 256 B/lane in flight for latency hiding.
template <int CS>
__global__ __launch_bounds__(128) void s_kernel(
    const float* __restrict__ x, const float* __restrict__ qkT,
    float* __restrict__ sp) {
  constexpr int CB = C_ / CS;  // 64 for CS=8
  int mt = blockIdx.x;
  int cs = blockIdx.y;
  int b  = blockIdx.z;
  int tid = threadIdx.x;

  __shared__ float qc[CB * NH];
  const float* src = qkT + ((size_t)b * C_ + cs * CB) * NH;
  for (int i = tid; i < CB * NH; i += 128) qc[i] = src[i];
  __syncthreads();

  int m0 = mt * 512 + tid * 4;
  float4 acc[NH];
#pragma unroll
  for (int h = 0; h < NH; ++h) acc[h] = make_float4(0.f, 0.f, 0.f, 0.f);

  const float* xb = x + (size_t)b * C_ * HW_ + (size_t)(cs * CB) * HW_ + m0;
  for (int c0 = 0; c0 < CB; c0 += 16) {
    float4 xv[16];
#pragma unroll
    for (int j = 0; j < 16; ++j)
      xv[j] = *(const float4*)(xb + (size_t)(c0 + j) * HW_);
#pragma unroll
    for (int j = 0; j < 16; ++j) {
      const float* q = qc + (c0 + j) * NH;
#pragma unroll
      for (int h = 0; h < NH; ++h) {
        float qh = q[h];
        acc[h].x += qh * xv[j].x; acc[h].y += qh * xv[j].y;
        acc[h].z += qh * xv[j].z; acc[h].w += qh * xv[j].w;
      }
    }
  }
  float* spp = sp + ((size_t)cs * B_ * NH + (size_t)b * NH) * HW_ + m0;
#pragma unroll
  for (int h = 0; h < NH; ++h)
    *(float4*)(spp + (size_t)h * HW_) = acc[h];
}

// ---------------------------------------------------------------------------
// Kernel C: combine partials + qb, softmax over m=4096.
// grid 192, block 1024 (16 waves); each thread owns one float4 of the row.
template <int CS>
__global__ __launch_bounds__(1024) void softmax_kernel(
    const float* __restrict__ sp, const float* __restrict__ qb,
    float* __restrict__ attn) {
  int bh = blockIdx.x;
  int tid = threadIdx.x;  // float4 index within the row
  float qbv = qb[bh];
  const size_t S4 = (size_t)B_ * NH * (HW_ / 4);
  const float4* p = (const float4*)sp + (size_t)bh * (HW_ / 4) + tid;

  float4 v = make_float4(qbv, qbv, qbv, qbv);
#pragma unroll
  for (int s = 0; s < CS; ++s) {
    float4 pv = p[s * S4];
    v.x += pv.x; v.y += pv.y; v.z += pv.z; v.w += pv.w;
  }

  float vmax = fmaxf(fmaxf(v.x, v.y), fmaxf(v.z, v.w));
  for (int off = 32; off; off >>= 1) vmax = fmaxf(vmax, __shfl_xor(vmax, off));
  __shared__ float redm[16], reds[16];
  int w = tid >> 6;
  if ((tid & 63) == 0) redm[w] = vmax;
  __syncthreads();
  vmax = redm[0];
#pragma unroll
  for (int i = 1; i < 16; ++i) vmax = fmaxf(vmax, redm[i]);

  v.x = __expf(v.x - vmax); v.y = __expf(v.y - vmax);
  v.z = __expf(v.z - vmax); v.w = __expf(v.w - vmax);
  float sum = v.x + v.y + v.z + v.w;
  for (int off = 32; off; off >>= 1) sum += __shfl_xor(sum, off);
  if ((tid & 63) == 0) reds[w] = sum;
  __syncthreads();
  float tot = reds[0];
#pragma unroll
  for (int i = 1; i < 16; ++i) tot += reds[i];
  float inv = 1.f / tot;
  v.x *= inv; v.y *= inv; v.z *= inv; v.w *= inv;
  ((float4*)attn)[(size_t)bh * (HW_ / 4) + tid] = v;
}

// ---------------------------------------------------------------------------
// Kernel D: y[b][h][c] = sum_m attn[b,h,m] * x[b,c,m]
// grid (cg=128, b=16), block 256; each block handles 4 consecutive c rows.
// x (HBM) loads issued before attn (L2) loads each iteration.
__global__ __launch_bounds__(256) void y_kernel(
    const float* __restrict__ x, const float* __restrict__ attn,
    float* __restrict__ y) {
  int cg = blockIdx.x;   // 0..127
  int b  = blockIdx.y;   // 0..15
  int tid = threadIdx.x;
  int c0 = cg * 4;

  float acc[4][NH] = {};
  const float4* xb = (const float4*)(x + (size_t)b * C_ * HW_ + (size_t)c0 * HW_);
  const float4* ab = (const float4*)(attn + (size_t)b * NH * HW_);
#pragma unroll 1
  for (int k = 0; k < 4; ++k) {
    int m4 = k * 256 + tid;
    float4 xv[4];
#pragma unroll
    for (int g = 0; g < 4; ++g) xv[g] = xb[(size_t)g * (HW_ / 4) + m4];
    float4 a[NH];
#pragma unroll
    for (int h = 0; h < NH; ++h) a[h] = ab[(size_t)h * (HW_ / 4) + m4];
#pragma unroll
    for (int g = 0; g < 4; ++g)
#pragma unroll
      for (int h = 0; h < NH; ++h)
        acc[g][h] += a[h].x * xv[g].x + a[h].y * xv[g].y +
                     a[h].z * xv[g].z + a[h].w * xv[g].w;
  }
  // reduce 48 values across the block
#pragma unroll
  for (int g = 0; g < 4; ++g)
#pragma unroll
    for (int h = 0; h < NH; ++h)
      for (int off = 32; off; off >>= 1)
        acc[g][h] += __shfl_xor(acc[g][h], off);

  __shared__ float red[4][48];
  int w = tid >> 6, lane = tid & 63;
  if (lane == 0) {
#pragma unroll
    for (int g = 0; g < 4; ++g)
#pragma unroll
      for (int h = 0; h < NH; ++h) red[w][g * NH + h] = acc[g][h];
  }
  __syncthreads();
  if (tid < 48) {
    float s = red[0][tid] + red[1][tid] + red[2][tid] + red[3][tid];
    int g = tid / NH, h = tid % NH;
    y[((size_t)b * NH + h) * C_ + c0 + g] = s;
  }
}

// ---------------------------------------------------------------------------
// Kernel E: outT[b][t] = bv[t] + sum_c Wv[t,c] * y[b][t/64][c]
__global__ __launch_bounds__(256) void out_kernel(
    const float* __restrict__ Wv, const float* __restrict__ bv,
    const float* __restrict__ y, float* __restrict__ outT) {
  int o = blockIdx.x * 4 + (threadIdx.x >> 6);
  int lane = threadIdx.x & 63;
  int b = o / T_, t = o % T_;
  int h = t / DH;
  const float* wr = Wv + (size_t)t * C_;
  const float* yr = y + ((size_t)b * NH + h) * C_;
  float s = 0.f;
#pragma unroll
  for (int j = 0; j < 8; ++j) { int c = j * 64 + lane; s += wr[c] * yr[c]; }
  for (int off = 32; off; off >>= 1) s += __shfl_xor(s, off);
  if (lane == 0) outT[o] = s + bv[t];
}

// ---------------------------------------------------------------------------
// Kernel F: z[b][c] = bo[c] + sum_t Wo[c,t] * outT[b][t]
__global__ __launch_bounds__(256) void z_kernel(
    const float* __restrict__ Wo, const float* __restrict__ bo,
    const float* __restrict__ outT, float* __restrict__ z) {
  int o = blockIdx.x * 4 + (threadIdx.x >> 6);
  int lane = threadIdx.x & 63;
  int b = o / C_, c = o % C_;
  const float* wr = Wo + (size_t)c * T_;
  const float* orr = outT + (size_t)b * T_;
  float s = 0.f;
#pragma unroll
  for (int j = 0; j < 12; ++j) { int t = j * 64 + lane; s += wr[t] * orr[t]; }
  for (int off = 32; off; off >>= 1) s += __shfl_xor(s, off);
  if (lane == 0) z[o] = s + bo[c];
}

// ---------------------------------------------------------------------------
// Kernel G: out[b,c,i,j] = cond[b,c,i,j] + z[b,c]
// 2 float4/thread; nontemporal (cond never re-read, out never read).
__global__ __launch_bounds__(256) void add_kernel(
    const float* __restrict__ cond, const float* __restrict__ z,
    float* __restrict__ out) {
  size_t i0 = (size_t)blockIdx.x * 512 + threadIdx.x;
  size_t i1 = i0 + 256;
  nfloat4 c0 = __builtin_nontemporal_load(&((const nfloat4*)cond)[i0]);
  nfloat4 c1 = __builtin_nontemporal_load(&((const nfloat4*)cond)[i1]);
  float z0 = z[(int)(i0 >> 10)];  // i0*4/4096
  float z1 = z[(int)(i1 >> 10)];
  nfloat4 r0 = c0 + z0;
  nfloat4 r1 = c1 + z1;
  __builtin_nontemporal_store(r0, &((nfloat4*)out)[i0]);
  __builtin_nontemporal_store(r1, &((nfloat4*)out)[i1]);
}

// ---------------------------------------------------------------------------
template <int CS>
static void run_pipeline(const float* cond, const float* t, const float* Wk,
                         const float* bk, const float* Wv, const float* bv,
                         const float* Wo, const float* bo, float* out,
                         float* ws, int out_size, hipStream_t stream) {
  float* qkT  = ws;
  float* qb   = ws + 98304;
  float* sp   = ws + 98496;
  float* attn = sp + (size_t)CS * 786432;
  float* y    = attn + 786432;
  float* outT = y + 98304;
  float* z    = outT + 12288;

  hipLaunchKernelGGL(qk_kernel, dim3(B_ * NH), dim3(512), 0, stream,
                     t, Wk, bk, qkT, qb);
  hipLaunchKernelGGL((s_kernel<CS>), dim3(8, CS, B_), dim3(128), 0, stream,
                     cond, qkT, sp);
  hipLaunchKernelGGL((softmax_kernel<CS>), dim3(B_ * NH), dim3(1024), 0, stream,
                     sp, qb, attn);
  hipLaunchKernelGGL(y_kernel, dim3(128, B_), dim3(256), 0, stream,
                     cond, attn, y);
  hipLaunchKernelGGL(out_kernel, dim3((B_ * T_) / 4), dim3(256), 0, stream,
                     Wv, bv, y, outT);
  hipLaunchKernelGGL(z_kernel, dim3((B_ * C_) / 4), dim3(256), 0, stream,
                     Wo, bo, outT, z);
  // out_size = 33554432 floats = 8388608 float4 = 16384 blocks * 512
  hipLaunchKernelGGL(add_kernel, dim3(out_size / 4 / 512), dim3(256), 0,
                     stream, cond, z, out);
}

extern "C" void kernel_launch(void* const* d_in, const int* in_sizes, int n_in,
                              void* d_out, int out_size, void* d_ws, size_t ws_size,
                              hipStream_t stream) {
  const float* cond = (const float*)d_in[0];
  const float* t    = (const float*)d_in[1];
  const float* Wk   = (const float*)d_in[2];
  const float* bk   = (const float*)d_in[3];
  const float* Wv   = (const float*)d_in[4];
  const float* bv   = (const float*)d_in[5];
  const float* Wo   = (const float*)d_in[6];
  const float* bo   = (const float*)d_in[7];
  float* out = (float*)d_out;
  float* ws  = (float*)d_ws;

  const size_t need8 = (size_t)(98496 + 8 * 786432 + 786432 + 98304 + 12288 + 8192) * 4;
  if (ws_size >= need8) {
    run_pipeline<8>(cond, t, Wk, bk, Wv, bv, Wo, bo, out, ws, out_size, stream);
  } else {
    run_pipeline<4>(cond, t, Wk, bk, Wv, bv, Wo, bo, out, ws, out_size, stream);
  }
}